// Round 6
// baseline (192.166 us; speedup 1.0000x reference)
//
#include <hip/hip_runtime.h>
#include <math.h>

// Problem constants: B=2, L=2048, E=1024, H=16, D=64
constexpr int Lc = 2048, Ec = 1024, Hc = 16, Dc = 64;

typedef __attribute__((ext_vector_type(8))) short bf16x8;
typedef __attribute__((ext_vector_type(4))) float f32x4;
typedef unsigned short u16;
typedef unsigned int u32;

#define MFMA16(a, b, c) __builtin_amdgcn_mfma_f32_16x16x32_bf16(a, b, c, 0, 0, 0)

__device__ inline u16 f2bf(float f) {
  u32 u = __builtin_bit_cast(u32, f);
  u32 r = u + 0x7fff + ((u >> 16) & 1);   // RNE
  return (u16)(r >> 16);
}

__device__ inline void gld16(const void* g, void* l) {
  __builtin_amdgcn_global_load_lds(
      (const __attribute__((address_space(1))) u32*)g,
      (__attribute__((address_space(3))) u32*)l, 16, 0, 0);
}

// =====================================================================
// Prepass: fp32 -> bf16 for x (4M), w_qkv Q+V rows (2M fused), w_out (1M).
// =====================================================================
constexpr size_t XN = (size_t)4096 * 1024;
constexpr size_t WQN = (size_t)2048 * 1024;
constexpr size_t WON = (size_t)1024 * 1024;

__global__ __launch_bounds__(256) void convert_all(
    const float* __restrict__ x, const float* __restrict__ wqkv,
    const float* __restrict__ wout, u16* __restrict__ xb,
    u16* __restrict__ wqb, u16* __restrict__ wob)
{
  const size_t i = ((size_t)blockIdx.x * 256 + threadIdx.x) * 4;
  float4 v;
  u16* dst;
  if (i < XN) {
    v = *(const float4*)(x + i);
    dst = xb + i;
  } else if (i < XN + WQN) {
    const size_t off = i - XN;
    const size_t row = off >> 10, col = off & 1023;
    const size_t srow = row + ((row >> 10) << 10);   // skip K rows of w_qkv
    v = *(const float4*)(wqkv + srow * 1024 + col);
    dst = wqb + off;
  } else {
    const size_t off = i - XN - WQN;
    v = *(const float4*)(wout + off);
    dst = wob + off;
  }
  u16 o0 = f2bf(v.x), o1 = f2bf(v.y), o2 = f2bf(v.z), o3 = f2bf(v.w);
  dst[0] = o0; dst[1] = o1; dst[2] = o2; dst[3] = o3;
}

// =====================================================================
// Transpose V once: Vt[bh][d][l] <- V[bh][l][d].
// Grid (32 l-tiles, 32 bh) x 256.
// =====================================================================
__global__ __launch_bounds__(256) void transpose_v(
    const u16* __restrict__ V, u16* __restrict__ Vt)
{
  __shared__ __align__(16) u16 T[64][72];
  const int bh = blockIdx.y, lt = blockIdx.x * 64;
  const int r = threadIdx.x >> 2;          // 0..63
  const int c = (threadIdx.x & 3) * 16;    // 0,16,32,48
  const u16* src = V + ((size_t)bh * Lc + lt) * Dc;
  *(bf16x8*)&T[r][c]     = *(const bf16x8*)(src + (size_t)r * 64 + c);
  *(bf16x8*)&T[r][c + 8] = *(const bf16x8*)(src + (size_t)r * 64 + c + 8);
  __syncthreads();
  bf16x8 o0, o1;
#pragma unroll
  for (int j = 0; j < 8; ++j) o0[j] = (short)T[c + j][r];
#pragma unroll
  for (int j = 0; j < 8; ++j) o1[j] = (short)T[c + 8 + j][r];
  u16* dst = Vt + ((size_t)bh * Dc + r) * Lc + lt + c;
  *(bf16x8*)dst = o0;
  *(bf16x8*)(dst + 8) = o1;
}

// =====================================================================
// QV GEMM (bf16 MFMA): M=4096, N=2048 (fused Q|V), K=1024.
// Double-buffered single-barrier K-loop.
// =====================================================================
__global__ __launch_bounds__(256) void gemm_qv(
    const u16* __restrict__ A, const u16* __restrict__ W,
    const float* __restrict__ bqkv, u16* __restrict__ Q, u16* __restrict__ V)
{
  __shared__ __align__(16) u16 As[2][4096];
  __shared__ __align__(16) u16 Bs[2][4096];
  const int tid = threadIdx.x;
  const int w = tid >> 6, lane = tid & 63;
  const int quad = lane >> 4, l16 = lane & 15;
  const int wm = w >> 1, wn = w & 1;
  const int rowTile = blockIdx.y * 128;
  const int colTile = blockIdx.x * 128;

  const int r0 = tid >> 2, o0 = (tid & 3) * 8;
  const u16* Ab0 = A + (size_t)(rowTile + r0) * 1024 + o0;
  const u16* Ab1 = Ab0 + (size_t)64 * 1024;
  const u16* Bb0 = W + (size_t)(colTile + r0) * 1024 + o0;
  const u16* Bb1 = Bb0 + (size_t)64 * 1024;

  f32x4 acc[4][4] = {};

  // prologue: stage k0=0 into buffer 0
  gld16(Ab0, &As[0][tid * 8]);
  gld16(Ab1, &As[0][2048 + tid * 8]);
  gld16(Bb0, &Bs[0][tid * 8]);
  gld16(Bb1, &Bs[0][2048 + tid * 8]);

  int cur = 0;
  for (int k0 = 0; k0 < 1024; k0 += 32) {
    __syncthreads();                       // drains stage(k0); protects buf cur^1
    if (k0 + 32 < 1024) {
      const int sb = cur ^ 1, kn = k0 + 32;
      gld16(Ab0 + kn, &As[sb][tid * 8]);
      gld16(Ab1 + kn, &As[sb][2048 + tid * 8]);
      gld16(Bb0 + kn, &Bs[sb][tid * 8]);
      gld16(Bb1 + kn, &Bs[sb][2048 + tid * 8]);
    }
    bf16x8 af[4], bf[4];
#pragma unroll
    for (int s = 0; s < 4; ++s)
      af[s] = *(const bf16x8*)&As[cur][(wm * 64 + s * 16 + l16) * 32 + quad * 8];
#pragma unroll
    for (int n = 0; n < 4; ++n)
      bf[n] = *(const bf16x8*)&Bs[cur][(wn * 64 + n * 16 + l16) * 32 + quad * 8];
#pragma unroll
    for (int s = 0; s < 4; ++s)
#pragma unroll
      for (int n = 0; n < 4; ++n)
        acc[s][n] = MFMA16(af[s], bf[n], acc[s][n]);
    cur ^= 1;
  }

#pragma unroll
  for (int n = 0; n < 4; ++n) {
    const int gn = colTile + wn * 64 + n * 16 + l16;   // fused col 0..2047
    const bool isV = gn >= 1024;
    const float bias = bqkv[gn + (isV ? 1024 : 0)];
    const float scl = isV ? 1.0f : 0.125f;             // fold 1/sqrt(d) into Q
    const int h = (gn & 1023) >> 6, d = gn & 63;
    u16* dst = isV ? V : Q;
#pragma unroll
    for (int s = 0; s < 4; ++s) {
#pragma unroll
      for (int r = 0; r < 4; ++r) {
        const int gm = rowTile + wm * 64 + s * 16 + quad * 4 + r;
        const int b = gm >> 11, l = gm & 2047;
        dst[(((size_t)(b * Hc + h)) * Lc + l) * Dc + d] = f2bf((acc[s][n][r] + bias) * scl);
      }
    }
  }
}

// =====================================================================
// Flash attention (bug-faithful: scores = Q.V^T, Q pre-scaled by 1/8).
// v4: LDS-throughput was the limiter (per unit: 16 b128 B-fragment reads
// for only 16 MFMA).  Each wave now owns 32 q-rows (two 16-row strips):
// the same bv/bvt fragment reads feed 32 MFMA -> LDS b128s per flop
// drop ~45%.  Block = one 128-row q-tile (4 waves x 32 rows), no lo/hi
// fusion; triangular balance via big-p-first dispatch order + 2 blocks/CU.
// XCD-locality: bh = xcd*4 + (slot&3) (4 bh per XCD -> ~3MB < 4MB L2).
// Staging/dbuf/XOR-swizzle machinery identical to v3.
// =====================================================================
constexpr int PSTR = 72;    // Ps row stride (u16)

__global__ __launch_bounds__(256) void attn_mfma(
    const u16* __restrict__ Q, const u16* __restrict__ V,
    const u16* __restrict__ Vt, u16* __restrict__ outA)
{
  // u16 offsets: [0,8192) Vs dbuf; [8192,16384) VsT dbuf;
  // [16384,25600) per-wave Ps (4 waves x 32 rows x PSTR).
  __shared__ __align__(16) u16 lds[25600];
  const int tid = threadIdx.x;
  const int w = tid >> 6, lane = tid & 63;
  const int quad = lane >> 4, l16 = lane & 15;

  // XCD-locality swizzle + big-q-tile-first ordering
  const int flat = blockIdx.x;
  const int xcd = flat & 7, slot = flat >> 3;      // slot 0..63
  const int bh = xcd * 4 + (slot & 3);
  const int p = 15 - (slot >> 2);                  // 128-row q-tile index, big first
  const int b = bh >> 4, h = bh & 15;

  const int q0 = p * 128;
  const int nt = 2 * p + 2;                        // 64-key tiles needed
  const int wq = q0 + w * 32;                      // this wave's first q-row

  const u16* Qb = Q + (size_t)bh * Lc * Dc;
  const u16* Vb = V + (size_t)bh * Lc * Dc;
  const u16* Vtb = Vt + (size_t)bh * Dc * Lc;
  u16* Ps = &lds[16384 + w * 32 * PSTR];

  // staging: LDS byte b (linear) holds tile byte b ^ ((b>>7&7)<<4)
  // -> pre-swizzle the GLOBAL source address.
  const int b1 = tid * 16, b2 = b1 + 4096;
  const int e1 = (b1 ^ (((b1 >> 7) & 7) << 4)) >> 1;   // u16 offset in tile
  const int e2 = (b2 ^ (((b2 >> 7) & 7) << 4)) >> 1;
  const u16* vs1 = Vb + e1;                            // + kt*64 per tile
  const u16* vs2 = Vb + e2;
  const u16* ts1 = Vtb + (size_t)(e1 >> 6) * Lc + (e1 & 63);  // + kt per tile
  const u16* ts2 = Vtb + (size_t)(e2 >> 6) * Lc + (e2 & 63);

  // swizzled LDS read offsets (u16 units): row = i*16+l16, col = kk*32+quad*8
  int roff[4][2];
#pragma unroll
  for (int i = 0; i < 4; ++i)
#pragma unroll
    for (int kk = 0; kk < 2; ++kk) {
      const int byte = ((i * 16 + l16) << 7) + kk * 64 + quad * 16;
      roff[i][kk] = (byte ^ ((l16 & 7) << 4)) >> 1;
    }

  // Q fragments: 2 strips x 2 k-halves (A-operand), rows wq + s*16 + l16
  bf16x8 qf[2][2];
#pragma unroll
  for (int s = 0; s < 2; ++s)
#pragma unroll
    for (int kk = 0; kk < 2; ++kk)
      qf[s][kk] = *(const bf16x8*)(Qb + (size_t)(wq + s * 16 + l16) * 64 + kk * 32 + quad * 8);

  f32x4 O[2][4] = {};
  float lsum[2][4] = {{0.f, 0.f, 0.f, 0.f}, {0.f, 0.f, 0.f, 0.f}};

  // prologue: stage tile 0 into buffer 0
  gld16(vs1, &lds[tid * 8]);
  gld16(vs2, &lds[2048 + tid * 8]);
  gld16(ts1, &lds[8192 + tid * 8]);
  gld16(ts2, &lds[8192 + 2048 + tid * 8]);

  int cur = 0;
  for (int t = 0; t < nt; ++t) {
    const int kt = t * 64;
    __syncthreads();                      // drains stage(t) into buf[cur]
    if (t + 1 < nt) {                     // next tile in flight during compute
      const int sb = cur ^ 1, nk = kt + 64;
      gld16(vs1 + (size_t)nk * 64, &lds[sb * 4096 + tid * 8]);
      gld16(vs2 + (size_t)nk * 64, &lds[sb * 4096 + 2048 + tid * 8]);
      gld16(ts1 + nk, &lds[8192 + sb * 4096 + tid * 8]);
      gld16(ts2 + nk, &lds[8192 + sb * 4096 + 2048 + tid * 8]);
    }
    if (kt <= wq + 31) {                  // wave-uniform compute gate
      const u16* VsB = &lds[cur * 4096];
      const u16* VtB = &lds[8192 + cur * 4096];

      // ---- S = Q V^T for both strips (bv read once, used 2x) ----
      bf16x8 bv[4][2];
#pragma unroll
      for (int nb = 0; nb < 4; ++nb)
#pragma unroll
        for (int kk = 0; kk < 2; ++kk)
          bv[nb][kk] = *(const bf16x8*)(VsB + roff[nb][kk]);

#pragma unroll
      for (int s = 0; s < 2; ++s) {
        f32x4 sf[4] = {};
#pragma unroll
        for (int nb = 0; nb < 4; ++nb) {
          sf[nb] = MFMA16(qf[s][0], bv[nb][0], sf[nb]);
          sf[nb] = MFMA16(qf[s][1], bv[nb][1], sf[nb]);
        }
        // exp + causal mask + partial row sums + P store
        const bool needmask = (kt + 63 > wq + s * 16);
#pragma unroll
        for (int nb = 0; nb < 4; ++nb)
#pragma unroll
          for (int r = 0; r < 4; ++r) {
            float pv = __expf(sf[nb][r]);   // scores bounded; Q pre-scaled
            if (needmask) {
              const int key = kt + nb * 16 + l16;
              const int qr = wq + s * 16 + quad * 4 + r;
              if (key > qr) pv = 0.f;
            }
            lsum[s][r] += pv;
            Ps[(s * 16 + quad * 4 + r) * PSTR + nb * 16 + l16] = f2bf(pv);
          }
      }

      // ---- O += P V for both strips (bvt read once, used 2x) ----
      bf16x8 bvt[4][2];
#pragma unroll
      for (int db = 0; db < 4; ++db)
#pragma unroll
        for (int kk = 0; kk < 2; ++kk)
          bvt[db][kk] = *(const bf16x8*)(VtB + roff[db][kk]);

#pragma unroll
      for (int s = 0; s < 2; ++s) {
        bf16x8 pf[2];
#pragma unroll
        for (int kk = 0; kk < 2; ++kk)
          pf[kk] = *(const bf16x8*)&Ps[(s * 16 + l16) * PSTR + kk * 32 + quad * 8];
#pragma unroll
        for (int db = 0; db < 4; ++db) {
          O[s][db] = MFMA16(pf[0], bvt[db][0], O[s][db]);
          O[s][db] = MFMA16(pf[1], bvt[db][1], O[s][db]);
        }
      }
    }
    cur ^= 1;
  }

  // epilogue: reduce row sums over the 16 lanes, normalize, store
#pragma unroll
  for (int s = 0; s < 2; ++s) {
#pragma unroll
    for (int r = 0; r < 4; ++r) {
      float l = lsum[s][r];
      l += __shfl_xor(l, 1);
      l += __shfl_xor(l, 2);
      l += __shfl_xor(l, 4);
      l += __shfl_xor(l, 8);
      const float inv = 1.f / l;
      const int q = wq + s * 16 + quad * 4 + r;
      const int orow = h * 128 + (q >> 4);
      const int cbase = (q & 15) << 6;
#pragma unroll
      for (int db = 0; db < 4; ++db)
        outA[((size_t)b * Lc + orow) * Ec + cbase + db * 16 + l16] =
            f2bf(O[s][db][r] * inv);
    }
  }
}

// =====================================================================
// Out GEMM: out[m][n] = sum_k Aw[m][k]*wob[n][k] + b_out[n], fp32 out.
// Double-buffered single-barrier K-loop (same schedule as gemm_qv).
// =====================================================================
__global__ __launch_bounds__(256) void gemm_out(
    const u16* __restrict__ A, const u16* __restrict__ W,
    const float* __restrict__ bias, float* __restrict__ out)
{
  __shared__ __align__(16) u16 As[2][4096];
  __shared__ __align__(16) u16 Bs[2][4096];
  const int tid = threadIdx.x;
  const int w = tid >> 6, lane = tid & 63;
  const int quad = lane >> 4, l16 = lane & 15;
  const int wm = w >> 1, wn = w & 1;
  const int rowTile = blockIdx.y * 128;
  const int colTile = blockIdx.x * 128;

  const int r0 = tid >> 2, o0 = (tid & 3) * 8;
  const u16* Ab0 = A + (size_t)(rowTile + r0) * 1024 + o0;
  const u16* Ab1 = Ab0 + (size_t)64 * 1024;
  const u16* Bb0 = W + (size_t)(colTile + r0) * 1024 + o0;
  const u16* Bb1 = Bb0 + (size_t)64 * 1024;

  f32x4 acc[4][4] = {};

  gld16(Ab0, &As[0][tid * 8]);
  gld16(Ab1, &As[0][2048 + tid * 8]);
  gld16(Bb0, &Bs[0][tid * 8]);
  gld16(Bb1, &Bs[0][2048 + tid * 8]);

  int cur = 0;
  for (int k0 = 0; k0 < 1024; k0 += 32) {
    __syncthreads();
    if (k0 + 32 < 1024) {
      const int sb = cur ^ 1, kn = k0 + 32;
      gld16(Ab0 + kn, &As[sb][tid * 8]);
      gld16(Ab1 + kn, &As[sb][2048 + tid * 8]);
      gld16(Bb0 + kn, &Bs[sb][tid * 8]);
      gld16(Bb1 + kn, &Bs[sb][2048 + tid * 8]);
    }
    bf16x8 af[4], bf[4];
#pragma unroll
    for (int s = 0; s < 4; ++s)
      af[s] = *(const bf16x8*)&As[cur][(wm * 64 + s * 16 + l16) * 32 + quad * 8];
#pragma unroll
    for (int n = 0; n < 4; ++n)
      bf[n] = *(const bf16x8*)&Bs[cur][(wn * 64 + n * 16 + l16) * 32 + quad * 8];
#pragma unroll
    for (int s = 0; s < 4; ++s)
#pragma unroll
      for (int n = 0; n < 4; ++n)
        acc[s][n] = MFMA16(af[s], bf[n], acc[s][n]);
    cur ^= 1;
  }

#pragma unroll
  for (int n = 0; n < 4; ++n) {
    const int gn = colTile + wn * 64 + n * 16 + l16;
    const float bn = bias[gn];
#pragma unroll
    for (int s = 0; s < 4; ++s)
#pragma unroll
      for (int r = 0; r < 4; ++r) {
        const int gm = rowTile + wm * 64 + s * 16 + quad * 4 + r;
        out[(size_t)gm * 1024 + gn] = acc[s][n][r] + bn;
      }
  }
}

// =====================================================================
extern "C" void kernel_launch(void* const* d_in, const int* in_sizes, int n_in,
                              void* d_out, int out_size, void* d_ws, size_t ws_size,
                              hipStream_t stream) {
  (void)in_sizes; (void)n_in; (void)out_size; (void)ws_size;
  const float* x     = (const float*)d_in[0];
  const float* w_qkv = (const float*)d_in[1];
  const float* b_qkv = (const float*)d_in[2];
  const float* w_out = (const float*)d_in[3];
  const float* b_out = (const float*)d_in[4];
  float* out = (float*)d_out;

  u16* xb  = (u16*)d_ws;
  u16* wqb = xb + XN;
  u16* wob = wqb + WQN;
  u16* Qw  = wob + WON;
  u16* Vw  = Qw + (size_t)2 * Hc * Lc * Dc;
  u16* Vtw = Vw + (size_t)2 * Hc * Lc * Dc;
  u16* Aw  = Vtw + (size_t)2 * Hc * Lc * Dc;

  convert_all<<<7168, 256, 0, stream>>>(x, w_qkv, w_out, xb, wqb, wob);
  gemm_qv<<<dim3(16, 32), 256, 0, stream>>>(xb, wqb, b_qkv, Qw, Vw);
  transpose_v<<<dim3(32, 32), 256, 0, stream>>>(Vw, Vtw);
  attn_mfma<<<512, 256, 0, stream>>>(Qw, Vw, Vtw, Aw);
  gemm_out<<<dim3(8, 32), 256, 0, stream>>>(Aw, wob, b_out, out);
}

// Round 8
// 176.220 us; speedup vs baseline: 1.0905x; 1.0905x over previous
//
#include <hip/hip_runtime.h>
#include <math.h>

// Problem constants: B=2, L=2048, E=1024, H=16, D=64
constexpr int Lc = 2048, Ec = 1024, Hc = 16, Dc = 64;

typedef __attribute__((ext_vector_type(8))) short bf16x8;
typedef __attribute__((ext_vector_type(4))) float f32x4;
typedef unsigned short u16;
typedef unsigned int u32;

#define MFMA16(a, b, c) __builtin_amdgcn_mfma_f32_16x16x32_bf16(a, b, c, 0, 0, 0)

__device__ inline u16 f2bf(float f) {
  u32 u = __builtin_bit_cast(u32, f);
  u32 r = u + 0x7fff + ((u >> 16) & 1);   // RNE
  return (u16)(r >> 16);
}

__device__ inline void gld16(const void* g, void* l) {
  __builtin_amdgcn_global_load_lds(
      (const __attribute__((address_space(1))) u32*)g,
      (__attribute__((address_space(3))) u32*)l, 16, 0, 0);
}

// =====================================================================
// Prepass: fp32 -> bf16 for x (4M), w_qkv Q+V rows (2M fused), w_out (1M).
// =====================================================================
constexpr size_t XN = (size_t)4096 * 1024;
constexpr size_t WQN = (size_t)2048 * 1024;
constexpr size_t WON = (size_t)1024 * 1024;

__global__ __launch_bounds__(256) void convert_all(
    const float* __restrict__ x, const float* __restrict__ wqkv,
    const float* __restrict__ wout, u16* __restrict__ xb,
    u16* __restrict__ wqb, u16* __restrict__ wob)
{
  const size_t i = ((size_t)blockIdx.x * 256 + threadIdx.x) * 4;
  float4 v;
  u16* dst;
  if (i < XN) {
    v = *(const float4*)(x + i);
    dst = xb + i;
  } else if (i < XN + WQN) {
    const size_t off = i - XN;
    const size_t row = off >> 10, col = off & 1023;
    const size_t srow = row + ((row >> 10) << 10);   // skip K rows of w_qkv
    v = *(const float4*)(wqkv + srow * 1024 + col);
    dst = wqb + off;
  } else {
    const size_t off = i - XN - WQN;
    v = *(const float4*)(wout + off);
    dst = wob + off;
  }
  u16 o0 = f2bf(v.x), o1 = f2bf(v.y), o2 = f2bf(v.z), o3 = f2bf(v.w);
  dst[0] = o0; dst[1] = o1; dst[2] = o2; dst[3] = o3;
}

// =====================================================================
// Transpose V once: Vt[bh][d][l] <- V[bh][l][d].
// Grid (32 l-tiles, 32 bh) x 256.
// =====================================================================
__global__ __launch_bounds__(256) void transpose_v(
    const u16* __restrict__ V, u16* __restrict__ Vt)
{
  __shared__ __align__(16) u16 T[64][72];
  const int bh = blockIdx.y, lt = blockIdx.x * 64;
  const int r = threadIdx.x >> 2;          // 0..63
  const int c = (threadIdx.x & 3) * 16;    // 0,16,32,48
  const u16* src = V + ((size_t)bh * Lc + lt) * Dc;
  *(bf16x8*)&T[r][c]     = *(const bf16x8*)(src + (size_t)r * 64 + c);
  *(bf16x8*)&T[r][c + 8] = *(const bf16x8*)(src + (size_t)r * 64 + c + 8);
  __syncthreads();
  bf16x8 o0, o1;
#pragma unroll
  for (int j = 0; j < 8; ++j) o0[j] = (short)T[c + j][r];
#pragma unroll
  for (int j = 0; j < 8; ++j) o1[j] = (short)T[c + 8 + j][r];
  u16* dst = Vt + ((size_t)bh * Dc + r) * Lc + lt + c;
  *(bf16x8*)dst = o0;
  *(bf16x8*)(dst + 8) = o1;
}

// =====================================================================
// QV GEMM v5 (bf16 MFMA): M=4096, N=2048 (fused Q|V), K=1024.
// BK=64 tiles: 128B LDS rows host the involutive XOR swizzle
// byte ^= ((byte>>7)&7)<<4 (pre-swizzled global source, swizzled reads)
// -> b128 fragment reads go from 8-way bank conflict (64B rows, old
// BK=32 layout) to 2-way (free).  16 K-iters (was 32) halves barrier
// drains.  Double-buffered single-barrier schedule unchanged.
// =====================================================================
__global__ __launch_bounds__(256) void gemm_qv(
    const u16* __restrict__ A, const u16* __restrict__ W,
    const float* __restrict__ bqkv, u16* __restrict__ Q, u16* __restrict__ V)
{
  __shared__ __align__(16) u16 As[2][8192];   // 128 rows x 64 u16
  __shared__ __align__(16) u16 Bs[2][8192];
  const int tid = threadIdx.x;
  const int w = tid >> 6, lane = tid & 63;
  const int quad = lane >> 4, l16 = lane & 15;
  const int wm = w >> 1, wn = w & 1;
  const int rowTile = blockIdx.y * 128;
  const int colTile = blockIdx.x * 128;

  // staging: dest byte b = tid*16 (+4096*j); row = b>>7 = srow+32j,
  // source element = b ^ ((row&7)<<4)  (row&7 invariant under +32)
  const int srow = tid >> 3;
  const int e = (((tid & 7) * 16) ^ ((srow & 7) << 4)) >> 1;   // u16 in [0,64)
  const u16* Asrc = A + (size_t)(rowTile + srow) * 1024 + e;
  const u16* Bsrc = W + (size_t)(colTile + srow) * 1024 + e;

  f32x4 acc[4][4] = {};

#define STAGE_QV(sb, k0)                                              \
  {                                                                   \
    gld16(Asrc + (k0),             &As[sb][tid * 8]);                 \
    gld16(Asrc + (k0) + 32 * 1024, &As[sb][tid * 8 + 2048]);          \
    gld16(Asrc + (k0) + 64 * 1024, &As[sb][tid * 8 + 4096]);          \
    gld16(Asrc + (k0) + 96 * 1024, &As[sb][tid * 8 + 6144]);          \
    gld16(Bsrc + (k0),             &Bs[sb][tid * 8]);                 \
    gld16(Bsrc + (k0) + 32 * 1024, &Bs[sb][tid * 8 + 2048]);          \
    gld16(Bsrc + (k0) + 64 * 1024, &Bs[sb][tid * 8 + 4096]);          \
    gld16(Bsrc + (k0) + 96 * 1024, &Bs[sb][tid * 8 + 6144]);          \
  }

  STAGE_QV(0, 0);
  int cur = 0;
  for (int k0 = 0; k0 < 1024; k0 += 64) {
    __syncthreads();                       // drains stage(k0) into buf[cur]
    if (k0 + 64 < 1024) STAGE_QV(cur ^ 1, k0 + 64);
    bf16x8 af[4][2], bf[4][2];
#pragma unroll
    for (int s = 0; s < 4; ++s)
#pragma unroll
      for (int kk = 0; kk < 2; ++kk)
        af[s][kk] = *(const bf16x8*)&As[cur][(wm * 64 + s * 16 + l16) * 64 +
                     ((kk * 32 + quad * 8) ^ ((l16 & 7) << 3))];
#pragma unroll
    for (int n = 0; n < 4; ++n)
#pragma unroll
      for (int kk = 0; kk < 2; ++kk)
        bf[n][kk] = *(const bf16x8*)&Bs[cur][(wn * 64 + n * 16 + l16) * 64 +
                     ((kk * 32 + quad * 8) ^ ((l16 & 7) << 3))];
#pragma unroll
    for (int kk = 0; kk < 2; ++kk)
#pragma unroll
      for (int s = 0; s < 4; ++s)
#pragma unroll
        for (int n = 0; n < 4; ++n)
          acc[s][n] = MFMA16(af[s][kk], bf[n][kk], acc[s][n]);
    cur ^= 1;
  }
#undef STAGE_QV

#pragma unroll
  for (int n = 0; n < 4; ++n) {
    const int gn = colTile + wn * 64 + n * 16 + l16;   // fused col 0..2047
    const bool isV = gn >= 1024;
    const float bias = bqkv[gn + (isV ? 1024 : 0)];
    const float scl = isV ? 1.0f : 0.125f;             // fold 1/sqrt(d) into Q
    const int h = (gn & 1023) >> 6, d = gn & 63;
    u16* dst = isV ? V : Q;
#pragma unroll
    for (int s = 0; s < 4; ++s) {
#pragma unroll
      for (int r = 0; r < 4; ++r) {
        const int gm = rowTile + wm * 64 + s * 16 + quad * 4 + r;
        const int b = gm >> 11, l = gm & 2047;
        dst[(((size_t)(b * Hc + h)) * Lc + l) * Dc + d] = f2bf((acc[s][n][r] + bias) * scl);
      }
    }
  }
}

// =====================================================================
// Flash attention v3 (proven 48.1 us) -- reverted verbatim from round 2.
// Bug-faithful: scores = Q.V^T, Q pre-scaled by 1/8.
//  - XCD-locality swizzle: all 16 x-blocks of one bh on ONE XCD.
//  - lo/hi q-tile fusion {p, 31-p}: uniform 33 units/block (balance!).
//  - B-fragments read once per tile, shared by both halves.
//  - Double-buffered, one barrier per key-tile; linear LDS + XOR swizzle
//    via pre-swizzled global source.
// =====================================================================
constexpr int PSTR = 72;    // Ps row stride (u16)

__device__ inline void attn_half(
    const bf16x8 qf[2], const bf16x8 bv[4][2], const bf16x8 bvt[4][2],
    u16* __restrict__ Ps, f32x4 O[4], float lsum[4],
    int kt, int wq, bool needmask, int quad, int l16)
{
  // ---- S = Q V^T ----
  f32x4 sf[4] = {};
#pragma unroll
  for (int nb = 0; nb < 4; ++nb) {
    sf[nb] = MFMA16(qf[0], bv[nb][0], sf[nb]);
    sf[nb] = MFMA16(qf[1], bv[nb][1], sf[nb]);
  }
  // ---- exp + causal mask + partial row sums + P store ----
#pragma unroll
  for (int nb = 0; nb < 4; ++nb)
#pragma unroll
    for (int r = 0; r < 4; ++r) {
      float p = __expf(sf[nb][r]);        // scores bounded; Q pre-scaled
      if (needmask) {
        const int key = kt + nb * 16 + l16;
        const int qr = wq + quad * 4 + r;
        if (key > qr) p = 0.f;
      }
      lsum[r] += p;
      Ps[(quad * 4 + r) * PSTR + nb * 16 + l16] = f2bf(p);
    }
  // ---- O += P V ----
  bf16x8 pf[2];
#pragma unroll
  for (int kk = 0; kk < 2; ++kk)
    pf[kk] = *(const bf16x8*)&Ps[l16 * PSTR + kk * 32 + quad * 8];
#pragma unroll
  for (int db = 0; db < 4; ++db) {
    O[db] = MFMA16(pf[0], bvt[db][0], O[db]);
    O[db] = MFMA16(pf[1], bvt[db][1], O[db]);
  }
}

__global__ __launch_bounds__(256) void attn_mfma(
    const u16* __restrict__ Q, const u16* __restrict__ V,
    const u16* __restrict__ Vt, u16* __restrict__ outA)
{
  // [0..8191] u16: Vs double buffer; [8192..16383]: VsT double buffer;
  // [16384..]: per-wave Ps, lo then hi.
  __shared__ __align__(16) u16 lds[2 * 4096 + 2 * 4096 + 2 * 4 * 16 * PSTR];
  const int tid = threadIdx.x;
  const int w = tid >> 6, lane = tid & 63;
  const int quad = lane >> 4, l16 = lane & 15;

  // XCD-locality swizzle (hw round-robins linear id across 8 XCDs)
  const int flat = blockIdx.x;
  const int xcd = flat & 7, slot = flat >> 3;
  const int bh = xcd * 4 + (slot >> 4);
  const int xblk = slot & 15;
  const int b = bh >> 4, h = bh & 15;

  const u16* Qb = Q + (size_t)bh * Lc * Dc;
  const u16* Vb = V + (size_t)bh * Lc * Dc;
  const u16* Vtb = Vt + (size_t)bh * Dc * Lc;
  u16* Psl = &lds[16384 + w * 16 * PSTR];
  u16* Psh = &lds[16384 + (4 + w) * 16 * PSTR];

  // staging: LDS byte b (linear) holds tile byte b ^ ((b>>7&7)<<4)
  // -> pre-swizzle the GLOBAL source address.
  const int b1 = tid * 16, b2 = b1 + 4096;
  const int e1 = (b1 ^ (((b1 >> 7) & 7) << 4)) >> 1;   // u16 offset in tile
  const int e2 = (b2 ^ (((b2 >> 7) & 7) << 4)) >> 1;
  const u16* vs1 = Vb + e1;                            // + kt*64 per tile
  const u16* vs2 = Vb + e2;
  const u16* ts1 = Vtb + (size_t)(e1 >> 6) * Lc + (e1 & 63);  // + kt per tile
  const u16* ts2 = Vtb + (size_t)(e2 >> 6) * Lc + (e2 & 63);

  // swizzled LDS read offsets (u16 units): row = i*16+l16, col = kk*32+quad*8
  int roff[4][2];
#pragma unroll
  for (int i = 0; i < 4; ++i)
#pragma unroll
    for (int kk = 0; kk < 2; ++kk) {
      const int byte = ((i * 16 + l16) << 7) + kk * 64 + quad * 16;
      roff[i][kk] = (byte ^ ((l16 & 7) << 4)) >> 1;
    }

  const int qlo = xblk, qhi = 31 - xblk;
  const int nt = qhi + 1;                 // staged key tiles: union of halves
  const int wqlo = qlo * 64 + w * 16;
  const int wqhi = qhi * 64 + w * 16;

  // Q fragments for both halves (A-operand)
  bf16x8 qfl[2], qfh[2];
#pragma unroll
  for (int kk = 0; kk < 2; ++kk) {
    qfl[kk] = *(const bf16x8*)(Qb + (size_t)(qlo * 64 + w * 16 + l16) * 64 + kk * 32 + quad * 8);
    qfh[kk] = *(const bf16x8*)(Qb + (size_t)(qhi * 64 + w * 16 + l16) * 64 + kk * 32 + quad * 8);
  }

  f32x4 Ol[4] = {}, Oh[4] = {};
  float lsl[4] = {0.f, 0.f, 0.f, 0.f}, lsh[4] = {0.f, 0.f, 0.f, 0.f};

  // prologue: stage tile 0 into buffer 0
  gld16(vs1, &lds[tid * 8]);
  gld16(vs2, &lds[2048 + tid * 8]);
  gld16(ts1, &lds[8192 + tid * 8]);
  gld16(ts2, &lds[8192 + 2048 + tid * 8]);

  int cur = 0;
  for (int t = 0; t < nt; ++t) {
    const int kt = t * 64;
    __syncthreads();                      // drains stage(t) into buf[cur]
    if (t + 1 < nt) {                     // next tile in flight during compute
      const int sb = cur ^ 1, nk = kt + 64;
      gld16(vs1 + (size_t)nk * 64, &lds[sb * 4096 + tid * 8]);
      gld16(vs2 + (size_t)nk * 64, &lds[sb * 4096 + 2048 + tid * 8]);
      gld16(ts1 + nk, &lds[8192 + sb * 4096 + tid * 8]);
      gld16(ts2 + nk, &lds[8192 + sb * 4096 + 2048 + tid * 8]);
    }
    const u16* VsB = &lds[cur * 4096];
    const u16* VtB = &lds[8192 + cur * 4096];

    // B-operand fragments: loaded ONCE, shared by both halves
    bf16x8 bv[4][2], bvt[4][2];
#pragma unroll
    for (int nb = 0; nb < 4; ++nb)
#pragma unroll
      for (int kk = 0; kk < 2; ++kk) {
        bv[nb][kk] = *(const bf16x8*)(VsB + roff[nb][kk]);
        bvt[nb][kk] = *(const bf16x8*)(VtB + roff[nb][kk]);
      }

    // hi half computes every tile; mask only on its diagonal tile
    attn_half(qfh, bv, bvt, Psh, Oh, lsh, kt, wqhi, t == qhi, quad, l16);
    if (t <= qlo)                         // wave-uniform gate
      attn_half(qfl, bv, bvt, Psl, Ol, lsl, kt, wqlo, t == qlo, quad, l16);
    cur ^= 1;
  }

  // epilogue: reduce row sums over the 16 lanes, normalize, store
#pragma unroll
  for (int half = 0; half < 2; ++half) {
    const int q0 = half ? qhi * 64 : qlo * 64;
    const f32x4* O = half ? Oh : Ol;
    const float* ls = half ? lsh : lsl;
#pragma unroll
    for (int r = 0; r < 4; ++r) {
      float l = ls[r];
      l += __shfl_xor(l, 1);
      l += __shfl_xor(l, 2);
      l += __shfl_xor(l, 4);
      l += __shfl_xor(l, 8);
      const float inv = 1.f / l;
      const int q = q0 + w * 16 + quad * 4 + r;
      const int orow = h * 128 + (q >> 4);
      const int cbase = (q & 15) << 6;
#pragma unroll
      for (int db = 0; db < 4; ++db)
        outA[((size_t)b * Lc + orow) * Ec + cbase + db * 16 + l16] =
            f2bf(O[db][r] * inv);
    }
  }
}

// =====================================================================
// Out GEMM v5: out[m][n] = sum_k Aw[m][k]*wob[n][k] + b_out[n], fp32 out.
// Tile 64(M) x 128(N), BK=64 + XOR swizzle (same as gemm_qv); grid
// (8,64) = 512 blocks = 2/CU (was 256 = 1/CU).
// =====================================================================
__global__ __launch_bounds__(256) void gemm_out(
    const u16* __restrict__ A, const u16* __restrict__ W,
    const float* __restrict__ bias, float* __restrict__ out)
{
  __shared__ __align__(16) u16 As[2][4096];   // 64 rows x 64 u16
  __shared__ __align__(16) u16 Bs[2][8192];   // 128 rows x 64 u16
  const int tid = threadIdx.x;
  const int w = tid >> 6, lane = tid & 63;
  const int quad = lane >> 4, l16 = lane & 15;
  const int wm = w >> 1, wn = w & 1;          // wm: 2x32 rows, wn: 2x64 cols
  const int rowTile = blockIdx.y * 64;
  const int colTile = blockIdx.x * 128;

  const int srow = tid >> 3;
  const int e = (((tid & 7) * 16) ^ ((srow & 7) << 4)) >> 1;   // u16 in [0,64)
  const u16* Asrc = A + (size_t)(rowTile + srow) * 1024 + e;
  const u16* Bsrc = W + (size_t)(colTile + srow) * 1024 + e;

  f32x4 acc[2][4] = {};

#define STAGE_OUT(sb, k0)                                             \
  {                                                                   \
    gld16(Asrc + (k0),             &As[sb][tid * 8]);                 \
    gld16(Asrc + (k0) + 32 * 1024, &As[sb][tid * 8 + 2048]);          \
    gld16(Bsrc + (k0),             &Bs[sb][tid * 8]);                 \
    gld16(Bsrc + (k0) + 32 * 1024, &Bs[sb][tid * 8 + 2048]);          \
    gld16(Bsrc + (k0) + 64 * 1024, &Bs[sb][tid * 8 + 4096]);          \
    gld16(Bsrc + (k0) + 96 * 1024, &Bs[sb][tid * 8 + 6144]);          \
  }

  STAGE_OUT(0, 0);
  int cur = 0;
  for (int k0 = 0; k0 < 1024; k0 += 64) {
    __syncthreads();
    if (k0 + 64 < 1024) STAGE_OUT(cur ^ 1, k0 + 64);
    bf16x8 af[2][2], bf[4][2];
#pragma unroll
    for (int s = 0; s < 2; ++s)
#pragma unroll
      for (int kk = 0; kk < 2; ++kk)
        af[s][kk] = *(const bf16x8*)&As[cur][(wm * 32 + s * 16 + l16) * 64 +
                     ((kk * 32 + quad * 8) ^ ((l16 & 7) << 3))];
#pragma unroll
    for (int n = 0; n < 4; ++n)
#pragma unroll
      for (int kk = 0; kk < 2; ++kk)
        bf[n][kk] = *(const bf16x8*)&Bs[cur][(wn * 64 + n * 16 + l16) * 64 +
                     ((kk * 32 + quad * 8) ^ ((l16 & 7) << 3))];
#pragma unroll
    for (int kk = 0; kk < 2; ++kk)
#pragma unroll
      for (int s = 0; s < 2; ++s)
#pragma unroll
        for (int n = 0; n < 4; ++n)
          acc[s][n] = MFMA16(af[s][kk], bf[n][kk], acc[s][n]);
    cur ^= 1;
  }
#undef STAGE_OUT

#pragma unroll
  for (int n = 0; n < 4; ++n) {
    const int gn = colTile + wn * 64 + n * 16 + l16;
    const float bn = bias[gn];
#pragma unroll
    for (int s = 0; s < 2; ++s)
#pragma unroll
      for (int r = 0; r < 4; ++r) {
        const int gm = rowTile + wm * 32 + s * 16 + quad * 4 + r;
        out[(size_t)gm * 1024 + gn] = acc[s][n][r] + bn;
      }
  }
}

// =====================================================================
extern "C" void kernel_launch(void* const* d_in, const int* in_sizes, int n_in,
                              void* d_out, int out_size, void* d_ws, size_t ws_size,
                              hipStream_t stream) {
  (void)in_sizes; (void)n_in; (void)out_size; (void)ws_size;
  const float* x     = (const float*)d_in[0];
  const float* w_qkv = (const float*)d_in[1];
  const float* b_qkv = (const float*)d_in[2];
  const float* w_out = (const float*)d_in[3];
  const float* b_out = (const float*)d_in[4];
  float* out = (float*)d_out;

  u16* xb  = (u16*)d_ws;
  u16* wqb = xb + XN;
  u16* wob = wqb + WQN;
  u16* Qw  = wob + WON;
  u16* Vw  = Qw + (size_t)2 * Hc * Lc * Dc;
  u16* Vtw = Vw + (size_t)2 * Hc * Lc * Dc;
  u16* Aw  = Vtw + (size_t)2 * Hc * Lc * Dc;

  convert_all<<<7168, 256, 0, stream>>>(x, w_qkv, w_out, xb, wqb, wob);
  gemm_qv<<<dim3(16, 32), 256, 0, stream>>>(xb, wqb, b_qkv, Qw, Vw);
  transpose_v<<<dim3(32, 32), 256, 0, stream>>>(Vw, Vtw);
  attn_mfma<<<512, 256, 0, stream>>>(Qw, Vw, Vtw, Aw);
  gemm_out<<<dim3(8, 64), 256, 0, stream>>>(Aw, wob, b_out, out);
}

// Round 9
// 173.804 us; speedup vs baseline: 1.1056x; 1.0139x over previous
//
#include <hip/hip_runtime.h>
#include <math.h>

// Problem constants: B=2, L=2048, E=1024, H=16, D=64
constexpr int Lc = 2048, Ec = 1024, Hc = 16, Dc = 64;

typedef __attribute__((ext_vector_type(8))) short bf16x8;
typedef __attribute__((ext_vector_type(4))) float f32x4;
typedef unsigned short u16;
typedef unsigned int u32;

#define MFMA16(a, b, c) __builtin_amdgcn_mfma_f32_16x16x32_bf16(a, b, c, 0, 0, 0)

__device__ inline u16 f2bf(float f) {
  u32 u = __builtin_bit_cast(u32, f);
  u32 r = u + 0x7fff + ((u >> 16) & 1);   // RNE
  return (u16)(r >> 16);
}

__device__ inline void gld16(const void* g, void* l) {
  __builtin_amdgcn_global_load_lds(
      (const __attribute__((address_space(1))) u32*)g,
      (__attribute__((address_space(3))) u32*)l, 16, 0, 0);
}

// =====================================================================
// Prepass: fp32 -> bf16 for x (4M), w_qkv Q+V rows (2M fused), w_out (1M).
// =====================================================================
constexpr size_t XN = (size_t)4096 * 1024;
constexpr size_t WQN = (size_t)2048 * 1024;
constexpr size_t WON = (size_t)1024 * 1024;

__global__ __launch_bounds__(256) void convert_all(
    const float* __restrict__ x, const float* __restrict__ wqkv,
    const float* __restrict__ wout, u16* __restrict__ xb,
    u16* __restrict__ wqb, u16* __restrict__ wob)
{
  const size_t i = ((size_t)blockIdx.x * 256 + threadIdx.x) * 4;
  float4 v;
  u16* dst;
  if (i < XN) {
    v = *(const float4*)(x + i);
    dst = xb + i;
  } else if (i < XN + WQN) {
    const size_t off = i - XN;
    const size_t row = off >> 10, col = off & 1023;
    const size_t srow = row + ((row >> 10) << 10);   // skip K rows of w_qkv
    v = *(const float4*)(wqkv + srow * 1024 + col);
    dst = wqb + off;
  } else {
    const size_t off = i - XN - WQN;
    v = *(const float4*)(wout + off);
    dst = wob + off;
  }
  u16 o0 = f2bf(v.x), o1 = f2bf(v.y), o2 = f2bf(v.z), o3 = f2bf(v.w);
  dst[0] = o0; dst[1] = o1; dst[2] = o2; dst[3] = o3;
}

// =====================================================================
// Transpose V once: Vt[bh][d][l] <- V[bh][l][d].
// Grid (32 l-tiles, 32 bh) x 256.
// =====================================================================
__global__ __launch_bounds__(256) void transpose_v(
    const u16* __restrict__ V, u16* __restrict__ Vt)
{
  __shared__ __align__(16) u16 T[64][72];
  const int bh = blockIdx.y, lt = blockIdx.x * 64;
  const int r = threadIdx.x >> 2;          // 0..63
  const int c = (threadIdx.x & 3) * 16;    // 0,16,32,48
  const u16* src = V + ((size_t)bh * Lc + lt) * Dc;
  *(bf16x8*)&T[r][c]     = *(const bf16x8*)(src + (size_t)r * 64 + c);
  *(bf16x8*)&T[r][c + 8] = *(const bf16x8*)(src + (size_t)r * 64 + c + 8);
  __syncthreads();
  bf16x8 o0, o1;
#pragma unroll
  for (int j = 0; j < 8; ++j) o0[j] = (short)T[c + j][r];
#pragma unroll
  for (int j = 0; j < 8; ++j) o1[j] = (short)T[c + 8 + j][r];
  u16* dst = Vt + ((size_t)bh * Dc + r) * Lc + lt + c;
  *(bf16x8*)dst = o0;
  *(bf16x8*)(dst + 8) = o1;
}

// =====================================================================
// QV GEMM v6 (bf16 MFMA): M=4096, N=2048 (fused Q|V), K=1024.
// Inner loop identical to v5 (BK=64, XOR swizzle).  NEW: XCD-patch
// dispatch -- flat 512 grid, xcd = id&7; each XCD owns an 8x8 block
// patch (4x2 patches tile the 32x16 grid).  Per-XCD working set =
// 8 A-panels + 8 B-panels = 4MB ~= L2, all 64 patch-blocks co-resident
// (2/CU x 32CU) -> panel reuse hits per-XCD L2 instead of L3/HBM.
// =====================================================================
__global__ __launch_bounds__(256) void gemm_qv(
    const u16* __restrict__ A, const u16* __restrict__ W,
    const float* __restrict__ bqkv, u16* __restrict__ Q, u16* __restrict__ V)
{
  __shared__ __align__(16) u16 As[2][8192];   // 128 rows x 64 u16
  __shared__ __align__(16) u16 Bs[2][8192];
  const int tid = threadIdx.x;
  const int w = tid >> 6, lane = tid & 63;
  const int quad = lane >> 4, l16 = lane & 15;
  const int wm = w >> 1, wn = w & 1;

  // XCD-patch swizzle: grid rows R=32, cols C=16; patches 8x8.
  const int flat = blockIdx.x;
  const int xcd = flat & 7, s64 = flat >> 3;        // s64 in [0,64)
  const int pr = xcd >> 1, pc = xcd & 1;            // 4x2 patch grid
  const int rowTile = (pr * 8 + (s64 >> 3)) * 128;
  const int colTile = (pc * 8 + (s64 & 7)) * 128;

  // staging: dest byte b = tid*16 (+4096*j); row = b>>7 = srow+32j,
  // source element = b ^ ((row&7)<<4)  (row&7 invariant under +32)
  const int srow = tid >> 3;
  const int e = (((tid & 7) * 16) ^ ((srow & 7) << 4)) >> 1;   // u16 in [0,64)
  const u16* Asrc = A + (size_t)(rowTile + srow) * 1024 + e;
  const u16* Bsrc = W + (size_t)(colTile + srow) * 1024 + e;

  f32x4 acc[4][4] = {};

#define STAGE_QV(sb, k0)                                              \
  {                                                                   \
    gld16(Asrc + (k0),             &As[sb][tid * 8]);                 \
    gld16(Asrc + (k0) + 32 * 1024, &As[sb][tid * 8 + 2048]);          \
    gld16(Asrc + (k0) + 64 * 1024, &As[sb][tid * 8 + 4096]);          \
    gld16(Asrc + (k0) + 96 * 1024, &As[sb][tid * 8 + 6144]);          \
    gld16(Bsrc + (k0),             &Bs[sb][tid * 8]);                 \
    gld16(Bsrc + (k0) + 32 * 1024, &Bs[sb][tid * 8 + 2048]);          \
    gld16(Bsrc + (k0) + 64 * 1024, &Bs[sb][tid * 8 + 4096]);          \
    gld16(Bsrc + (k0) + 96 * 1024, &Bs[sb][tid * 8 + 6144]);          \
  }

  STAGE_QV(0, 0);
  int cur = 0;
  for (int k0 = 0; k0 < 1024; k0 += 64) {
    __syncthreads();                       // drains stage(k0) into buf[cur]
    if (k0 + 64 < 1024) STAGE_QV(cur ^ 1, k0 + 64);
    bf16x8 af[4][2], bf[4][2];
#pragma unroll
    for (int s = 0; s < 4; ++s)
#pragma unroll
      for (int kk = 0; kk < 2; ++kk)
        af[s][kk] = *(const bf16x8*)&As[cur][(wm * 64 + s * 16 + l16) * 64 +
                     ((kk * 32 + quad * 8) ^ ((l16 & 7) << 3))];
#pragma unroll
    for (int n = 0; n < 4; ++n)
#pragma unroll
      for (int kk = 0; kk < 2; ++kk)
        bf[n][kk] = *(const bf16x8*)&Bs[cur][(wn * 64 + n * 16 + l16) * 64 +
                     ((kk * 32 + quad * 8) ^ ((l16 & 7) << 3))];
#pragma unroll
    for (int kk = 0; kk < 2; ++kk)
#pragma unroll
      for (int s = 0; s < 4; ++s)
#pragma unroll
        for (int n = 0; n < 4; ++n)
          acc[s][n] = MFMA16(af[s][kk], bf[n][kk], acc[s][n]);
    cur ^= 1;
  }
#undef STAGE_QV

#pragma unroll
  for (int n = 0; n < 4; ++n) {
    const int gn = colTile + wn * 64 + n * 16 + l16;   // fused col 0..2047
    const bool isV = gn >= 1024;
    const float bias = bqkv[gn + (isV ? 1024 : 0)];
    const float scl = isV ? 1.0f : 0.125f;             // fold 1/sqrt(d) into Q
    const int h = (gn & 1023) >> 6, d = gn & 63;
    u16* dst = isV ? V : Q;
#pragma unroll
    for (int s = 0; s < 4; ++s) {
#pragma unroll
      for (int r = 0; r < 4; ++r) {
        const int gm = rowTile + wm * 64 + s * 16 + quad * 4 + r;
        const int b = gm >> 11, l = gm & 2047;
        dst[(((size_t)(b * Hc + h)) * Lc + l) * Dc + d] = f2bf((acc[s][n][r] + bias) * scl);
      }
    }
  }
}

// =====================================================================
// Flash attention v3 (proven 48.1-48.8 us) -- unchanged.
// Bug-faithful: scores = Q.V^T, Q pre-scaled by 1/8.
//  - XCD-locality swizzle: all 16 x-blocks of one bh on ONE XCD.
//  - lo/hi q-tile fusion {p, 31-p}: uniform 33 units/block (balance).
//  - B-fragments read once per tile, shared by both halves.
//  - Double-buffered, one barrier per key-tile; linear LDS + XOR swizzle
//    via pre-swizzled global source.
// =====================================================================
constexpr int PSTR = 72;    // Ps row stride (u16)

__device__ inline void attn_half(
    const bf16x8 qf[2], const bf16x8 bv[4][2], const bf16x8 bvt[4][2],
    u16* __restrict__ Ps, f32x4 O[4], float lsum[4],
    int kt, int wq, bool needmask, int quad, int l16)
{
  // ---- S = Q V^T ----
  f32x4 sf[4] = {};
#pragma unroll
  for (int nb = 0; nb < 4; ++nb) {
    sf[nb] = MFMA16(qf[0], bv[nb][0], sf[nb]);
    sf[nb] = MFMA16(qf[1], bv[nb][1], sf[nb]);
  }
  // ---- exp + causal mask + partial row sums + P store ----
#pragma unroll
  for (int nb = 0; nb < 4; ++nb)
#pragma unroll
    for (int r = 0; r < 4; ++r) {
      float p = __expf(sf[nb][r]);        // scores bounded; Q pre-scaled
      if (needmask) {
        const int key = kt + nb * 16 + l16;
        const int qr = wq + quad * 4 + r;
        if (key > qr) p = 0.f;
      }
      lsum[r] += p;
      Ps[(quad * 4 + r) * PSTR + nb * 16 + l16] = f2bf(p);
    }
  // ---- O += P V ----
  bf16x8 pf[2];
#pragma unroll
  for (int kk = 0; kk < 2; ++kk)
    pf[kk] = *(const bf16x8*)&Ps[l16 * PSTR + kk * 32 + quad * 8];
#pragma unroll
  for (int db = 0; db < 4; ++db) {
    O[db] = MFMA16(pf[0], bvt[db][0], O[db]);
    O[db] = MFMA16(pf[1], bvt[db][1], O[db]);
  }
}

__global__ __launch_bounds__(256) void attn_mfma(
    const u16* __restrict__ Q, const u16* __restrict__ V,
    const u16* __restrict__ Vt, u16* __restrict__ outA)
{
  // [0..8191] u16: Vs double buffer; [8192..16383]: VsT double buffer;
  // [16384..]: per-wave Ps, lo then hi.
  __shared__ __align__(16) u16 lds[2 * 4096 + 2 * 4096 + 2 * 4 * 16 * PSTR];
  const int tid = threadIdx.x;
  const int w = tid >> 6, lane = tid & 63;
  const int quad = lane >> 4, l16 = lane & 15;

  // XCD-locality swizzle (hw round-robins linear id across 8 XCDs)
  const int flat = blockIdx.x;
  const int xcd = flat & 7, slot = flat >> 3;
  const int bh = xcd * 4 + (slot >> 4);
  const int xblk = slot & 15;
  const int b = bh >> 4, h = bh & 15;

  const u16* Qb = Q + (size_t)bh * Lc * Dc;
  const u16* Vb = V + (size_t)bh * Lc * Dc;
  const u16* Vtb = Vt + (size_t)bh * Dc * Lc;
  u16* Psl = &lds[16384 + w * 16 * PSTR];
  u16* Psh = &lds[16384 + (4 + w) * 16 * PSTR];

  // staging: LDS byte b (linear) holds tile byte b ^ ((b>>7&7)<<4)
  // -> pre-swizzle the GLOBAL source address.
  const int b1 = tid * 16, b2 = b1 + 4096;
  const int e1 = (b1 ^ (((b1 >> 7) & 7) << 4)) >> 1;   // u16 offset in tile
  const int e2 = (b2 ^ (((b2 >> 7) & 7) << 4)) >> 1;
  const u16* vs1 = Vb + e1;                            // + kt*64 per tile
  const u16* vs2 = Vb + e2;
  const u16* ts1 = Vtb + (size_t)(e1 >> 6) * Lc + (e1 & 63);  // + kt per tile
  const u16* ts2 = Vtb + (size_t)(e2 >> 6) * Lc + (e2 & 63);

  // swizzled LDS read offsets (u16 units): row = i*16+l16, col = kk*32+quad*8
  int roff[4][2];
#pragma unroll
  for (int i = 0; i < 4; ++i)
#pragma unroll
    for (int kk = 0; kk < 2; ++kk) {
      const int byte = ((i * 16 + l16) << 7) + kk * 64 + quad * 16;
      roff[i][kk] = (byte ^ ((l16 & 7) << 4)) >> 1;
    }

  const int qlo = xblk, qhi = 31 - xblk;
  const int nt = qhi + 1;                 // staged key tiles: union of halves
  const int wqlo = qlo * 64 + w * 16;
  const int wqhi = qhi * 64 + w * 16;

  // Q fragments for both halves (A-operand)
  bf16x8 qfl[2], qfh[2];
#pragma unroll
  for (int kk = 0; kk < 2; ++kk) {
    qfl[kk] = *(const bf16x8*)(Qb + (size_t)(qlo * 64 + w * 16 + l16) * 64 + kk * 32 + quad * 8);
    qfh[kk] = *(const bf16x8*)(Qb + (size_t)(qhi * 64 + w * 16 + l16) * 64 + kk * 32 + quad * 8);
  }

  f32x4 Ol[4] = {}, Oh[4] = {};
  float lsl[4] = {0.f, 0.f, 0.f, 0.f}, lsh[4] = {0.f, 0.f, 0.f, 0.f};

  // prologue: stage tile 0 into buffer 0
  gld16(vs1, &lds[tid * 8]);
  gld16(vs2, &lds[2048 + tid * 8]);
  gld16(ts1, &lds[8192 + tid * 8]);
  gld16(ts2, &lds[8192 + 2048 + tid * 8]);

  int cur = 0;
  for (int t = 0; t < nt; ++t) {
    const int kt = t * 64;
    __syncthreads();                      // drains stage(t) into buf[cur]
    if (t + 1 < nt) {                     // next tile in flight during compute
      const int sb = cur ^ 1, nk = kt + 64;
      gld16(vs1 + (size_t)nk * 64, &lds[sb * 4096 + tid * 8]);
      gld16(vs2 + (size_t)nk * 64, &lds[sb * 4096 + 2048 + tid * 8]);
      gld16(ts1 + nk, &lds[8192 + sb * 4096 + tid * 8]);
      gld16(ts2 + nk, &lds[8192 + sb * 4096 + 2048 + tid * 8]);
    }
    const u16* VsB = &lds[cur * 4096];
    const u16* VtB = &lds[8192 + cur * 4096];

    // B-operand fragments: loaded ONCE, shared by both halves
    bf16x8 bv[4][2], bvt[4][2];
#pragma unroll
    for (int nb = 0; nb < 4; ++nb)
#pragma unroll
      for (int kk = 0; kk < 2; ++kk) {
        bv[nb][kk] = *(const bf16x8*)(VsB + roff[nb][kk]);
        bvt[nb][kk] = *(const bf16x8*)(VtB + roff[nb][kk]);
      }

    // hi half computes every tile; mask only on its diagonal tile
    attn_half(qfh, bv, bvt, Psh, Oh, lsh, kt, wqhi, t == qhi, quad, l16);
    if (t <= qlo)                         // wave-uniform gate
      attn_half(qfl, bv, bvt, Psl, Ol, lsl, kt, wqlo, t == qlo, quad, l16);
    cur ^= 1;
  }

  // epilogue: reduce row sums over the 16 lanes, normalize, store
#pragma unroll
  for (int half = 0; half < 2; ++half) {
    const int q0 = half ? qhi * 64 : qlo * 64;
    const f32x4* O = half ? Oh : Ol;
    const float* ls = half ? lsh : lsl;
#pragma unroll
    for (int r = 0; r < 4; ++r) {
      float l = ls[r];
      l += __shfl_xor(l, 1);
      l += __shfl_xor(l, 2);
      l += __shfl_xor(l, 4);
      l += __shfl_xor(l, 8);
      const float inv = 1.f / l;
      const int q = q0 + w * 16 + quad * 4 + r;
      const int orow = h * 128 + (q >> 4);
      const int cbase = (q & 15) << 6;
#pragma unroll
      for (int db = 0; db < 4; ++db)
        outA[((size_t)b * Lc + orow) * Ec + cbase + db * 16 + l16] =
            f2bf(O[db][r] * inv);
    }
  }
}

// =====================================================================
// Out GEMM v6: out[m][n] = sum_k Aw[m][k]*wob[n][k] + b_out[n], fp32 out.
// Inner loop identical to v5 (64x128 tile, BK=64, swizzle).  NEW:
// XCD-patch dispatch -- flat 512 grid; xcd = id&7 owns 8 rows x all
// 8 cols (patch working set 8x128KB A + 8x256KB B = 3MB < 4MB L2).
// =====================================================================
__global__ __launch_bounds__(256) void gemm_out(
    const u16* __restrict__ A, const u16* __restrict__ W,
    const float* __restrict__ bias, float* __restrict__ out)
{
  __shared__ __align__(16) u16 As[2][4096];   // 64 rows x 64 u16
  __shared__ __align__(16) u16 Bs[2][8192];   // 128 rows x 64 u16
  const int tid = threadIdx.x;
  const int w = tid >> 6, lane = tid & 63;
  const int quad = lane >> 4, l16 = lane & 15;
  const int wm = w >> 1, wn = w & 1;          // wm: 2x32 rows, wn: 2x64 cols

  // XCD-patch swizzle: grid rows R=64, cols C=8; xcd owns 8 rows x 8 cols.
  const int flat = blockIdx.x;
  const int xcd = flat & 7, s64 = flat >> 3;        // s64 in [0,64)
  const int rowTile = (xcd * 8 + (s64 >> 3)) * 64;
  const int colTile = (s64 & 7) * 128;

  const int srow = tid >> 3;
  const int e = (((tid & 7) * 16) ^ ((srow & 7) << 4)) >> 1;   // u16 in [0,64)
  const u16* Asrc = A + (size_t)(rowTile + srow) * 1024 + e;
  const u16* Bsrc = W + (size_t)(colTile + srow) * 1024 + e;

  f32x4 acc[2][4] = {};

#define STAGE_OUT(sb, k0)                                             \
  {                                                                   \
    gld16(Asrc + (k0),             &As[sb][tid * 8]);                 \
    gld16(Asrc + (k0) + 32 * 1024, &As[sb][tid * 8 + 2048]);          \
    gld16(Bsrc + (k0),             &Bs[sb][tid * 8]);                 \
    gld16(Bsrc + (k0) + 32 * 1024, &Bs[sb][tid * 8 + 2048]);          \
    gld16(Bsrc + (k0) + 64 * 1024, &Bs[sb][tid * 8 + 4096]);          \
    gld16(Bsrc + (k0) + 96 * 1024, &Bs[sb][tid * 8 + 6144]);          \
  }

  STAGE_OUT(0, 0);
  int cur = 0;
  for (int k0 = 0; k0 < 1024; k0 += 64) {
    __syncthreads();
    if (k0 + 64 < 1024) STAGE_OUT(cur ^ 1, k0 + 64);
    bf16x8 af[2][2], bf[4][2];
#pragma unroll
    for (int s = 0; s < 2; ++s)
#pragma unroll
      for (int kk = 0; kk < 2; ++kk)
        af[s][kk] = *(const bf16x8*)&As[cur][(wm * 32 + s * 16 + l16) * 64 +
                     ((kk * 32 + quad * 8) ^ ((l16 & 7) << 3))];
#pragma unroll
    for (int n = 0; n < 4; ++n)
#pragma unroll
      for (int kk = 0; kk < 2; ++kk)
        bf[n][kk] = *(const bf16x8*)&Bs[cur][(wn * 64 + n * 16 + l16) * 64 +
                     ((kk * 32 + quad * 8) ^ ((l16 & 7) << 3))];
#pragma unroll
    for (int kk = 0; kk < 2; ++kk)
#pragma unroll
      for (int s = 0; s < 2; ++s)
#pragma unroll
        for (int n = 0; n < 4; ++n)
          acc[s][n] = MFMA16(af[s][kk], bf[n][kk], acc[s][n]);
    cur ^= 1;
  }
#undef STAGE_OUT

#pragma unroll
  for (int n = 0; n < 4; ++n) {
    const int gn = colTile + wn * 64 + n * 16 + l16;
    const float bn = bias[gn];
#pragma unroll
    for (int s = 0; s < 2; ++s)
#pragma unroll
      for (int r = 0; r < 4; ++r) {
        const int gm = rowTile + wm * 32 + s * 16 + quad * 4 + r;
        out[(size_t)gm * 1024 + gn] = acc[s][n][r] + bn;
      }
  }
}

// =====================================================================
extern "C" void kernel_launch(void* const* d_in, const int* in_sizes, int n_in,
                              void* d_out, int out_size, void* d_ws, size_t ws_size,
                              hipStream_t stream) {
  (void)in_sizes; (void)n_in; (void)out_size; (void)ws_size;
  const float* x     = (const float*)d_in[0];
  const float* w_qkv = (const float*)d_in[1];
  const float* b_qkv = (const float*)d_in[2];
  const float* w_out = (const float*)d_in[3];
  const float* b_out = (const float*)d_in[4];
  float* out = (float*)d_out;

  u16* xb  = (u16*)d_ws;
  u16* wqb = xb + XN;
  u16* wob = wqb + WQN;
  u16* Qw  = wob + WON;
  u16* Vw  = Qw + (size_t)2 * Hc * Lc * Dc;
  u16* Vtw = Vw + (size_t)2 * Hc * Lc * Dc;
  u16* Aw  = Vtw + (size_t)2 * Hc * Lc * Dc;

  convert_all<<<7168, 256, 0, stream>>>(x, w_qkv, w_out, xb, wqb, wob);
  gemm_qv<<<512, 256, 0, stream>>>(xb, wqb, b_qkv, Qw, Vw);
  transpose_v<<<dim3(32, 32), 256, 0, stream>>>(Vw, Vtw);
  attn_mfma<<<512, 256, 0, stream>>>(Qw, Vw, Vtw, Aw);
  gemm_out<<<512, 256, 0, stream>>>(Aw, wob, b_out, out);
}

// Round 10
// 171.631 us; speedup vs baseline: 1.1196x; 1.0127x over previous
//
#include <hip/hip_runtime.h>
#include <math.h>

// Problem constants: B=2, L=2048, E=1024, H=16, D=64
constexpr int Lc = 2048, Ec = 1024, Hc = 16, Dc = 64;

typedef __attribute__((ext_vector_type(8))) short bf16x8;
typedef __attribute__((ext_vector_type(4))) float f32x4;
typedef unsigned short u16;
typedef unsigned int u32;

#define MFMA16(a, b, c) __builtin_amdgcn_mfma_f32_16x16x32_bf16(a, b, c, 0, 0, 0)

__device__ inline u16 f2bf(float f) {
  u32 u = __builtin_bit_cast(u32, f);
  u32 r = u + 0x7fff + ((u >> 16) & 1);   // RNE
  return (u16)(r >> 16);
}

__device__ inline void gld16(const void* g, void* l) {
  __builtin_amdgcn_global_load_lds(
      (const __attribute__((address_space(1))) u32*)g,
      (__attribute__((address_space(3))) u32*)l, 16, 0, 0);
}

// =====================================================================
// Prepass: fp32 -> bf16 for x (4M), w_qkv Q+V rows (2M fused), w_out (1M).
// =====================================================================
constexpr size_t XN = (size_t)4096 * 1024;
constexpr size_t WQN = (size_t)2048 * 1024;
constexpr size_t WON = (size_t)1024 * 1024;

__global__ __launch_bounds__(256) void convert_all(
    const float* __restrict__ x, const float* __restrict__ wqkv,
    const float* __restrict__ wout, u16* __restrict__ xb,
    u16* __restrict__ wqb, u16* __restrict__ wob)
{
  const size_t i = ((size_t)blockIdx.x * 256 + threadIdx.x) * 4;
  float4 v;
  u16* dst;
  if (i < XN) {
    v = *(const float4*)(x + i);
    dst = xb + i;
  } else if (i < XN + WQN) {
    const size_t off = i - XN;
    const size_t row = off >> 10, col = off & 1023;
    const size_t srow = row + ((row >> 10) << 10);   // skip K rows of w_qkv
    v = *(const float4*)(wqkv + srow * 1024 + col);
    dst = wqb + off;
  } else {
    const size_t off = i - XN - WQN;
    v = *(const float4*)(wout + off);
    dst = wob + off;
  }
  u16 o0 = f2bf(v.x), o1 = f2bf(v.y), o2 = f2bf(v.z), o3 = f2bf(v.w);
  dst[0] = o0; dst[1] = o1; dst[2] = o2; dst[3] = o3;
}

// =====================================================================
// QV GEMM v7 (bf16 MFMA): M=4096, N=2048 (fused Q|V), K=1024.
// Inner loop identical to v6 (BK=64, XOR swizzle, XCD-patch dispatch).
// NEW: epilogue ALSO writes Vt[bh][d][l] for V columns (packed ushort4,
// 4 consecutive l per lane; n/s loops complete 128B lines) -- the
// standalone transpose_v kernel (8MB R + 8MB W + one dispatch) is gone.
// =====================================================================
__global__ __launch_bounds__(256) void gemm_qv(
    const u16* __restrict__ A, const u16* __restrict__ W,
    const float* __restrict__ bqkv, u16* __restrict__ Q, u16* __restrict__ V,
    u16* __restrict__ Vt)
{
  __shared__ __align__(16) u16 As[2][8192];   // 128 rows x 64 u16
  __shared__ __align__(16) u16 Bs[2][8192];
  const int tid = threadIdx.x;
  const int w = tid >> 6, lane = tid & 63;
  const int quad = lane >> 4, l16 = lane & 15;
  const int wm = w >> 1, wn = w & 1;

  // XCD-patch swizzle: grid rows R=32, cols C=16; patches 8x8.
  const int flat = blockIdx.x;
  const int xcd = flat & 7, s64 = flat >> 3;        // s64 in [0,64)
  const int pr = xcd >> 1, pc = xcd & 1;            // 4x2 patch grid
  const int rowTile = (pr * 8 + (s64 >> 3)) * 128;
  const int colTile = (pc * 8 + (s64 & 7)) * 128;

  // staging: dest byte b = tid*16 (+4096*j); row = b>>7 = srow+32j,
  // source element = b ^ ((row&7)<<4)  (row&7 invariant under +32)
  const int srow = tid >> 3;
  const int e = (((tid & 7) * 16) ^ ((srow & 7) << 4)) >> 1;   // u16 in [0,64)
  const u16* Asrc = A + (size_t)(rowTile + srow) * 1024 + e;
  const u16* Bsrc = W + (size_t)(colTile + srow) * 1024 + e;

  f32x4 acc[4][4] = {};

#define STAGE_QV(sb, k0)                                              \
  {                                                                   \
    gld16(Asrc + (k0),             &As[sb][tid * 8]);                 \
    gld16(Asrc + (k0) + 32 * 1024, &As[sb][tid * 8 + 2048]);          \
    gld16(Asrc + (k0) + 64 * 1024, &As[sb][tid * 8 + 4096]);          \
    gld16(Asrc + (k0) + 96 * 1024, &As[sb][tid * 8 + 6144]);          \
    gld16(Bsrc + (k0),             &Bs[sb][tid * 8]);                 \
    gld16(Bsrc + (k0) + 32 * 1024, &Bs[sb][tid * 8 + 2048]);          \
    gld16(Bsrc + (k0) + 64 * 1024, &Bs[sb][tid * 8 + 4096]);          \
    gld16(Bsrc + (k0) + 96 * 1024, &Bs[sb][tid * 8 + 6144]);          \
  }

  STAGE_QV(0, 0);
  int cur = 0;
  for (int k0 = 0; k0 < 1024; k0 += 64) {
    __syncthreads();                       // drains stage(k0) into buf[cur]
    if (k0 + 64 < 1024) STAGE_QV(cur ^ 1, k0 + 64);
    bf16x8 af[4][2], bf[4][2];
#pragma unroll
    for (int s = 0; s < 4; ++s)
#pragma unroll
      for (int kk = 0; kk < 2; ++kk)
        af[s][kk] = *(const bf16x8*)&As[cur][(wm * 64 + s * 16 + l16) * 64 +
                     ((kk * 32 + quad * 8) ^ ((l16 & 7) << 3))];
#pragma unroll
    for (int n = 0; n < 4; ++n)
#pragma unroll
      for (int kk = 0; kk < 2; ++kk)
        bf[n][kk] = *(const bf16x8*)&Bs[cur][(wn * 64 + n * 16 + l16) * 64 +
                     ((kk * 32 + quad * 8) ^ ((l16 & 7) << 3))];
#pragma unroll
    for (int kk = 0; kk < 2; ++kk)
#pragma unroll
      for (int s = 0; s < 4; ++s)
#pragma unroll
        for (int n = 0; n < 4; ++n)
          acc[s][n] = MFMA16(af[s][kk], bf[n][kk], acc[s][n]);
    cur ^= 1;
  }
#undef STAGE_QV

#pragma unroll
  for (int n = 0; n < 4; ++n) {
    const int gn = colTile + wn * 64 + n * 16 + l16;   // fused col 0..2047
    const bool isV = gn >= 1024;
    const float bias = bqkv[gn + (isV ? 1024 : 0)];
    const float scl = isV ? 1.0f : 0.125f;             // fold 1/sqrt(d) into Q
    const int h = (gn & 1023) >> 6, d = gn & 63;
    u16* dst = isV ? V : Q;
#pragma unroll
    for (int s = 0; s < 4; ++s) {
      const int gm0 = rowTile + wm * 64 + s * 16 + quad * 4;
      const int b = gm0 >> 11;             // whole tile within one batch
      ushort4 tv;
#pragma unroll
      for (int r = 0; r < 4; ++r) {
        const int l = (gm0 + r) & 2047;
        const u16 val = f2bf((acc[s][n][r] + bias) * scl);
        dst[(((size_t)(b * Hc + h)) * Lc + l) * Dc + d] = val;
        ((u16*)&tv)[r] = val;
      }
      if (isV) {                           // fused transpose store
        const int l0 = gm0 & 2047;
        *(ushort4*)(Vt + (((size_t)(b * Hc + h)) * Dc + d) * Lc + l0) = tv;
      }
    }
  }
}

// =====================================================================
// Flash attention v3 (proven 48.1-48.9 us) -- unchanged.
// Bug-faithful: scores = Q.V^T, Q pre-scaled by 1/8.
//  - XCD-locality swizzle: all 16 x-blocks of one bh on ONE XCD.
//  - lo/hi q-tile fusion {p, 31-p}: uniform 33 units/block (balance).
//  - B-fragments read once per tile, shared by both halves.
//  - Double-buffered, one barrier per key-tile; linear LDS + XOR swizzle
//    via pre-swizzled global source.
// =====================================================================
constexpr int PSTR = 72;    // Ps row stride (u16)

__device__ inline void attn_half(
    const bf16x8 qf[2], const bf16x8 bv[4][2], const bf16x8 bvt[4][2],
    u16* __restrict__ Ps, f32x4 O[4], float lsum[4],
    int kt, int wq, bool needmask, int quad, int l16)
{
  // ---- S = Q V^T ----
  f32x4 sf[4] = {};
#pragma unroll
  for (int nb = 0; nb < 4; ++nb) {
    sf[nb] = MFMA16(qf[0], bv[nb][0], sf[nb]);
    sf[nb] = MFMA16(qf[1], bv[nb][1], sf[nb]);
  }
  // ---- exp + causal mask + partial row sums + P store ----
#pragma unroll
  for (int nb = 0; nb < 4; ++nb)
#pragma unroll
    for (int r = 0; r < 4; ++r) {
      float p = __expf(sf[nb][r]);        // scores bounded; Q pre-scaled
      if (needmask) {
        const int key = kt + nb * 16 + l16;
        const int qr = wq + quad * 4 + r;
        if (key > qr) p = 0.f;
      }
      lsum[r] += p;
      Ps[(quad * 4 + r) * PSTR + nb * 16 + l16] = f2bf(p);
    }
  // ---- O += P V ----
  bf16x8 pf[2];
#pragma unroll
  for (int kk = 0; kk < 2; ++kk)
    pf[kk] = *(const bf16x8*)&Ps[l16 * PSTR + kk * 32 + quad * 8];
#pragma unroll
  for (int db = 0; db < 4; ++db) {
    O[db] = MFMA16(pf[0], bvt[db][0], O[db]);
    O[db] = MFMA16(pf[1], bvt[db][1], O[db]);
  }
}

__global__ __launch_bounds__(256) void attn_mfma(
    const u16* __restrict__ Q, const u16* __restrict__ V,
    const u16* __restrict__ Vt, u16* __restrict__ outA)
{
  // [0..8191] u16: Vs double buffer; [8192..16383]: VsT double buffer;
  // [16384..]: per-wave Ps, lo then hi.
  __shared__ __align__(16) u16 lds[2 * 4096 + 2 * 4096 + 2 * 4 * 16 * PSTR];
  const int tid = threadIdx.x;
  const int w = tid >> 6, lane = tid & 63;
  const int quad = lane >> 4, l16 = lane & 15;

  // XCD-locality swizzle (hw round-robins linear id across 8 XCDs)
  const int flat = blockIdx.x;
  const int xcd = flat & 7, slot = flat >> 3;
  const int bh = xcd * 4 + (slot >> 4);
  const int xblk = slot & 15;
  const int b = bh >> 4, h = bh & 15;

  const u16* Qb = Q + (size_t)bh * Lc * Dc;
  const u16* Vb = V + (size_t)bh * Lc * Dc;
  const u16* Vtb = Vt + (size_t)bh * Dc * Lc;
  u16* Psl = &lds[16384 + w * 16 * PSTR];
  u16* Psh = &lds[16384 + (4 + w) * 16 * PSTR];

  // staging: LDS byte b (linear) holds tile byte b ^ ((b>>7&7)<<4)
  // -> pre-swizzle the GLOBAL source address.
  const int b1 = tid * 16, b2 = b1 + 4096;
  const int e1 = (b1 ^ (((b1 >> 7) & 7) << 4)) >> 1;   // u16 offset in tile
  const int e2 = (b2 ^ (((b2 >> 7) & 7) << 4)) >> 1;
  const u16* vs1 = Vb + e1;                            // + kt*64 per tile
  const u16* vs2 = Vb + e2;
  const u16* ts1 = Vtb + (size_t)(e1 >> 6) * Lc + (e1 & 63);  // + kt per tile
  const u16* ts2 = Vtb + (size_t)(e2 >> 6) * Lc + (e2 & 63);

  // swizzled LDS read offsets (u16 units): row = i*16+l16, col = kk*32+quad*8
  int roff[4][2];
#pragma unroll
  for (int i = 0; i < 4; ++i)
#pragma unroll
    for (int kk = 0; kk < 2; ++kk) {
      const int byte = ((i * 16 + l16) << 7) + kk * 64 + quad * 16;
      roff[i][kk] = (byte ^ ((l16 & 7) << 4)) >> 1;
    }

  const int qlo = xblk, qhi = 31 - xblk;
  const int nt = qhi + 1;                 // staged key tiles: union of halves
  const int wqlo = qlo * 64 + w * 16;
  const int wqhi = qhi * 64 + w * 16;

  // Q fragments for both halves (A-operand)
  bf16x8 qfl[2], qfh[2];
#pragma unroll
  for (int kk = 0; kk < 2; ++kk) {
    qfl[kk] = *(const bf16x8*)(Qb + (size_t)(qlo * 64 + w * 16 + l16) * 64 + kk * 32 + quad * 8);
    qfh[kk] = *(const bf16x8*)(Qb + (size_t)(qhi * 64 + w * 16 + l16) * 64 + kk * 32 + quad * 8);
  }

  f32x4 Ol[4] = {}, Oh[4] = {};
  float lsl[4] = {0.f, 0.f, 0.f, 0.f}, lsh[4] = {0.f, 0.f, 0.f, 0.f};

  // prologue: stage tile 0 into buffer 0
  gld16(vs1, &lds[tid * 8]);
  gld16(vs2, &lds[2048 + tid * 8]);
  gld16(ts1, &lds[8192 + tid * 8]);
  gld16(ts2, &lds[8192 + 2048 + tid * 8]);

  int cur = 0;
  for (int t = 0; t < nt; ++t) {
    const int kt = t * 64;
    __syncthreads();                      // drains stage(t) into buf[cur]
    if (t + 1 < nt) {                     // next tile in flight during compute
      const int sb = cur ^ 1, nk = kt + 64;
      gld16(vs1 + (size_t)nk * 64, &lds[sb * 4096 + tid * 8]);
      gld16(vs2 + (size_t)nk * 64, &lds[sb * 4096 + 2048 + tid * 8]);
      gld16(ts1 + nk, &lds[8192 + sb * 4096 + tid * 8]);
      gld16(ts2 + nk, &lds[8192 + sb * 4096 + 2048 + tid * 8]);
    }
    const u16* VsB = &lds[cur * 4096];
    const u16* VtB = &lds[8192 + cur * 4096];

    // B-operand fragments: loaded ONCE, shared by both halves
    bf16x8 bv[4][2], bvt[4][2];
#pragma unroll
    for (int nb = 0; nb < 4; ++nb)
#pragma unroll
      for (int kk = 0; kk < 2; ++kk) {
        bv[nb][kk] = *(const bf16x8*)(VsB + roff[nb][kk]);
        bvt[nb][kk] = *(const bf16x8*)(VtB + roff[nb][kk]);
      }

    // hi half computes every tile; mask only on its diagonal tile
    attn_half(qfh, bv, bvt, Psh, Oh, lsh, kt, wqhi, t == qhi, quad, l16);
    if (t <= qlo)                         // wave-uniform gate
      attn_half(qfl, bv, bvt, Psl, Ol, lsl, kt, wqlo, t == qlo, quad, l16);
    cur ^= 1;
  }

  // epilogue: reduce row sums over the 16 lanes, normalize, store
#pragma unroll
  for (int half = 0; half < 2; ++half) {
    const int q0 = half ? qhi * 64 : qlo * 64;
    const f32x4* O = half ? Oh : Ol;
    const float* ls = half ? lsh : lsl;
#pragma unroll
    for (int r = 0; r < 4; ++r) {
      float l = ls[r];
      l += __shfl_xor(l, 1);
      l += __shfl_xor(l, 2);
      l += __shfl_xor(l, 4);
      l += __shfl_xor(l, 8);
      const float inv = 1.f / l;
      const int q = q0 + w * 16 + quad * 4 + r;
      const int orow = h * 128 + (q >> 4);
      const int cbase = (q & 15) << 6;
#pragma unroll
      for (int db = 0; db < 4; ++db)
        outA[((size_t)b * Lc + orow) * Ec + cbase + db * 16 + l16] =
            f2bf(O[db][r] * inv);
    }
  }
}

// =====================================================================
// Out GEMM v6: out[m][n] = sum_k Aw[m][k]*wob[n][k] + b_out[n], fp32 out.
// Unchanged from round 9 (64x128 tile, BK=64, swizzle, XCD-patch).
// =====================================================================
__global__ __launch_bounds__(256) void gemm_out(
    const u16* __restrict__ A, const u16* __restrict__ W,
    const float* __restrict__ bias, float* __restrict__ out)
{
  __shared__ __align__(16) u16 As[2][4096];   // 64 rows x 64 u16
  __shared__ __align__(16) u16 Bs[2][8192];   // 128 rows x 64 u16
  const int tid = threadIdx.x;
  const int w = tid >> 6, lane = tid & 63;
  const int quad = lane >> 4, l16 = lane & 15;
  const int wm = w >> 1, wn = w & 1;          // wm: 2x32 rows, wn: 2x64 cols

  // XCD-patch swizzle: grid rows R=64, cols C=8; xcd owns 8 rows x 8 cols.
  const int flat = blockIdx.x;
  const int xcd = flat & 7, s64 = flat >> 3;        // s64 in [0,64)
  const int rowTile = (xcd * 8 + (s64 >> 3)) * 64;
  const int colTile = (s64 & 7) * 128;

  const int srow = tid >> 3;
  const int e = (((tid & 7) * 16) ^ ((srow & 7) << 4)) >> 1;   // u16 in [0,64)
  const u16* Asrc = A + (size_t)(rowTile + srow) * 1024 + e;
  const u16* Bsrc = W + (size_t)(colTile + srow) * 1024 + e;

  f32x4 acc[2][4] = {};

#define STAGE_OUT(sb, k0)                                             \
  {                                                                   \
    gld16(Asrc + (k0),             &As[sb][tid * 8]);                 \
    gld16(Asrc + (k0) + 32 * 1024, &As[sb][tid * 8 + 2048]);          \
    gld16(Bsrc + (k0),             &Bs[sb][tid * 8]);                 \
    gld16(Bsrc + (k0) + 32 * 1024, &Bs[sb][tid * 8 + 2048]);          \
    gld16(Bsrc + (k0) + 64 * 1024, &Bs[sb][tid * 8 + 4096]);          \
    gld16(Bsrc + (k0) + 96 * 1024, &Bs[sb][tid * 8 + 6144]);          \
  }

  STAGE_OUT(0, 0);
  int cur = 0;
  for (int k0 = 0; k0 < 1024; k0 += 64) {
    __syncthreads();
    if (k0 + 64 < 1024) STAGE_OUT(cur ^ 1, k0 + 64);
    bf16x8 af[2][2], bf[4][2];
#pragma unroll
    for (int s = 0; s < 2; ++s)
#pragma unroll
      for (int kk = 0; kk < 2; ++kk)
        af[s][kk] = *(const bf16x8*)&As[cur][(wm * 32 + s * 16 + l16) * 64 +
                     ((kk * 32 + quad * 8) ^ ((l16 & 7) << 3))];
#pragma unroll
    for (int n = 0; n < 4; ++n)
#pragma unroll
      for (int kk = 0; kk < 2; ++kk)
        bf[n][kk] = *(const bf16x8*)&Bs[cur][(wn * 64 + n * 16 + l16) * 64 +
                     ((kk * 32 + quad * 8) ^ ((l16 & 7) << 3))];
#pragma unroll
    for (int kk = 0; kk < 2; ++kk)
#pragma unroll
      for (int s = 0; s < 2; ++s)
#pragma unroll
        for (int n = 0; n < 4; ++n)
          acc[s][n] = MFMA16(af[s][kk], bf[n][kk], acc[s][n]);
    cur ^= 1;
  }
#undef STAGE_OUT

#pragma unroll
  for (int n = 0; n < 4; ++n) {
    const int gn = colTile + wn * 64 + n * 16 + l16;
    const float bn = bias[gn];
#pragma unroll
    for (int s = 0; s < 2; ++s)
#pragma unroll
      for (int r = 0; r < 4; ++r) {
        const int gm = rowTile + wm * 32 + s * 16 + quad * 4 + r;
        out[(size_t)gm * 1024 + gn] = acc[s][n][r] + bn;
      }
  }
}

// =====================================================================
extern "C" void kernel_launch(void* const* d_in, const int* in_sizes, int n_in,
                              void* d_out, int out_size, void* d_ws, size_t ws_size,
                              hipStream_t stream) {
  (void)in_sizes; (void)n_in; (void)out_size; (void)ws_size;
  const float* x     = (const float*)d_in[0];
  const float* w_qkv = (const float*)d_in[1];
  const float* b_qkv = (const float*)d_in[2];
  const float* w_out = (const float*)d_in[3];
  const float* b_out = (const float*)d_in[4];
  float* out = (float*)d_out;

  u16* xb  = (u16*)d_ws;
  u16* wqb = xb + XN;
  u16* wob = wqb + WQN;
  u16* Qw  = wob + WON;
  u16* Vw  = Qw + (size_t)2 * Hc * Lc * Dc;
  u16* Vtw = Vw + (size_t)2 * Hc * Lc * Dc;
  u16* Aw  = Vtw + (size_t)2 * Hc * Lc * Dc;

  convert_all<<<7168, 256, 0, stream>>>(x, w_qkv, w_out, xb, wqb, wob);
  gemm_qv<<<512, 256, 0, stream>>>(xb, wqb, b_qkv, Qw, Vw, Vtw);
  attn_mfma<<<512, 256, 0, stream>>>(Qw, Vw, Vtw, Aw);
  gemm_out<<<512, 256, 0, stream>>>(Aw, wob, b_out, out);
}